// Round 6
// baseline (131.227 us; speedup 1.0000x reference)
//
#include <hip/hip_runtime.h>

// Medical2DSliceRenderer on MI355X (gfx950) — round 6
//
//   S1[c] = sum_g exp2(qa dx^2 + qb dx dy + qd dy^2 + lop)   (= g*op)
//   S2[c] = sum_g (g*op)^2 * (ft/op)                          (= g^2*op*ft)
//   img = sum_c [prod_{c'<c}(1-S1_c')] * S2_c   (4-step recursion at the end)
//
// Round 6:
//  - per-(gaussian,row) uniform folding: dy, qb*dy, qd*dy^2+lop computed once
//    per row (wave-uniform VALU), mm = fma(fma(qa,dx,Qb),dx,R) = 2 FMA/px.
//    30 VALU + 4 exp2 per 4-px iteration (was 38+4).
//  - barrier-free main loop: chunk partials are independent; each wave runs
//    its 256 gaussians (contiguous via permuted table layout) with NO
//    __syncthreads, writes per-chunk partials to LDS, ONE barrier, then
//    waves 0..3 reduce + run the 4-step recursion. Kills the 8-barrier
//    lockstep that correlated all 16 waves' s_load stalls.

#define EPSV 1e-6f
#define NG   4096
#define PP   16384
#define NSL  4
#define SPLIT 16
#define GPC  64          // gaussians per split per chunk
#define GPS  256         // gaussians per split total (contiguous in table)

__global__ void prep_kernel(const float* __restrict__ means,
                            const float* __restrict__ scales,
                            const float* __restrict__ rots,
                            const float* __restrict__ ops,
                            const float* __restrict__ fts,
                            float4* __restrict__ gdata) {
    __shared__ float red[256];
    int tid = threadIdx.x;

    float m = -1e30f;
    for (int i = tid; i < NG; i += 256) m = fmaxf(m, scales[i*3+2]);
    red[tid] = m;
    __syncthreads();
    for (int s = 128; s > 0; s >>= 1) {
        if (tid < s) red[tid] = fmaxf(red[tid], red[tid+s]);
        __syncthreads();
    }
    float maxd = 3.0f * red[0];

    int g = blockIdx.x * 256 + tid;
    if (g >= NG) return;

    float qw = rots[g*4+0], qx = rots[g*4+1], qy = rots[g*4+2], qz = rots[g*4+3];
    float inorm = rsqrtf(qw*qw + qx*qx + qy*qy + qz*qz);
    qw *= inorm; qx *= inorm; qy *= inorm; qz *= inorm;

    float s0 = scales[g*3+0], s1 = scales[g*3+1], s2 = scales[g*3+2];

    float r00 = 1.f - 2.f*(qy*qy + qz*qz), r01 = 2.f*(qx*qy - qw*qz), r02 = 2.f*(qx*qz + qw*qy);
    float r10 = 2.f*(qx*qy + qw*qz), r11 = 1.f - 2.f*(qx*qx + qz*qz), r12 = 2.f*(qy*qz - qw*qx);
    float r20 = 2.f*(qx*qz - qw*qy), r21 = 2.f*(qy*qz + qw*qx), r22 = 1.f - 2.f*(qx*qx + qy*qy);

    float a00 = r00*s0, a01 = r01*s1, a02 = r02*s2;
    float a10 = r10*s0, a11 = r11*s1, a12 = r12*s2;
    float a20 = r20*s0, a21 = r21*s1, a22 = r22*s2;

    float c00 = a00*a00 + a01*a01 + a02*a02;
    float c01 = a00*a10 + a01*a11 + a02*a12;
    float c02 = a00*a20 + a01*a21 + a02*a22;
    float c11 = a10*a10 + a11*a11 + a12*a12;
    float c12 = a10*a20 + a11*a21 + a12*a22;
    float c22 = a20*a20 + a21*a21 + a22*a22;

    float izz = 1.0f / (c22 + EPSV);
    float kx = c02 * izz, ky = c12 * izz;
    float sa = c00 - c02*c02*izz + EPSV;
    float sb = c01 - c02*c12*izz;
    float sd = c11 - c12*c12*izz + EPSV;
    float det = sa*sd - sb*sb;
    float idet = 1.0f / det;

    const float C0 = -0.72134752044448170f;   // -0.5 * log2(e)
    float qa = C0 * sd * idet;
    float qb = C0 * (-2.0f * sb * idet);
    float qd = C0 * sa * idet;

    float mx = means[g*3+0], my = means[g*3+1], mz = means[g*3+2];
    float op = ops[g], ft = fts[g];

    // permuted layout: [slice][split][chunk][idx] so each wave's 256
    // gaussians are contiguous (streaming s_load, no barriers needed)
    int chunk = g >> 10;
    int w     = g & 1023;
    int split = w >> 6;
    int idx   = w & 63;
    int pos   = split * GPS + chunk * GPC + idx;

    #pragma unroll
    for (int s = 0; s < NSL; ++s) {
        float z = -0.15f + 0.1f * (float)s;
        float zoff = z - mz;
        float m2x = mx + kx * zoff;
        float m2y = my + ky * zoff;
        bool live = (fabsf(mz - z) < maxd) && (op > 1e-12f);
        float lop  = live ? __log2f(op) : -__builtin_inff();
        float ftop = live ? ft / op     : 0.f;
        float4* o = gdata + ((size_t)(s*NG + pos)) * 2;
        o[0] = make_float4(-m2x, -m2y, qa, qb);
        o[1] = make_float4( qd,   lop,  ftop, 0.f);
    }
}

__global__ __launch_bounds__(1024, 1)
void render_kernel(const float4* __restrict__ gdata, float* __restrict__ out) {
    // parts[split][lane][chunk*8 + slot]; stride 33 -> conflict-free columns
    __shared__ float parts[SPLIT][64][33];   // 135,168 B

    int tid   = threadIdx.x;
    int lane  = tid & 63;
    int split = __builtin_amdgcn_readfirstlane(tid >> 6);   // 0..15
    int slice = blockIdx.x >> 6;
    int r0    = (blockIdx.x & 63) * 2;

    const float DL = 2.0f / 127.0f;
    float x0 = -1.0f + (float)lane * DL;
    float x1 = x0 + 64.0f * DL;
    float y0 = -1.0f + (float)r0 * DL;
    float y1 = y0 + DL;

    const float4* p = gdata + ((size_t)slice * NG + split * GPS) * 2;

    #pragma unroll
    for (int c = 0; c < 4; ++c) {
        float s100 = 0.f, s101 = 0.f, s110 = 0.f, s111 = 0.f;  // S1 [row][colhalf]
        float s200 = 0.f, s201 = 0.f, s210 = 0.f, s211 = 0.f;  // S2
        #pragma unroll 8
        for (int g = 0; g < GPC; ++g) {
            float4 A = p[(c*GPC + g)*2 + 0];   // -m2x, -m2y, qa, qb  (s_load)
            float4 B = p[(c*GPC + g)*2 + 1];   // qd, lop, ftop, pad
            // per-gaussian row-uniform folds (wave-uniform VALU)
            float dy0 = y0 + A.y;
            float dy1 = y1 + A.y;
            float Qb0 = A.w * dy0;
            float Qb1 = A.w * dy1;
            float R0  = fmaf(B.x * dy0, dy0, B.y);
            float R1  = fmaf(B.x * dy1, dy1, B.y);
            // per-pixel: 2 FMA + exp + 3 accum
            float dx0 = x0 + A.x;
            float dx1 = x1 + A.x;
            float m00 = fmaf(fmaf(A.z, dx0, Qb0), dx0, R0);
            float m01 = fmaf(fmaf(A.z, dx1, Qb1), dx1, R1);   // note: Qb1? no:
            // (row0,col1) uses dy0: fix below
            float m10 = fmaf(fmaf(A.z, dx0, Qb1), dx0, R1);
            float m11 = fmaf(fmaf(A.z, dx1, Qb1), dx1, R1);
            // correct (row0,col1):
            m01 = fmaf(fmaf(A.z, dx1, Qb0), dx1, R0);
            float g00 = __builtin_amdgcn_exp2f(m00);
            float g01 = __builtin_amdgcn_exp2f(m01);
            float g10 = __builtin_amdgcn_exp2f(m10);
            float g11 = __builtin_amdgcn_exp2f(m11);
            s100 += g00;  s101 += g01;  s110 += g10;  s111 += g11;
            s200 = fmaf(g00*g00, B.z, s200);
            s201 = fmaf(g01*g01, B.z, s201);
            s210 = fmaf(g10*g10, B.z, s210);
            s211 = fmaf(g11*g11, B.z, s211);
        }
        float* q = &parts[split][lane][c*8];
        q[0] = s100;  q[1] = s101;  q[2] = s110;  q[3] = s111;
        q[4] = s200;  q[5] = s201;  q[6] = s210;  q[7] = s211;
    }

    __syncthreads();   // the ONLY barrier

    if (split < 4) {   // wave w owns px-slot w: (r0 + w/2, lane + (w&1)*64)
        float img = 0.f, acc = 0.f;
        #pragma unroll
        for (int c = 0; c < 4; ++c) {
            float S1 = 0.f, S2 = 0.f;
            #pragma unroll
            for (int s = 0; s < SPLIT; ++s) {
                S1 += parts[s][lane][c*8 + split];
                S2 += parts[s][lane][c*8 + 4 + split];
            }
            float om = 1.0f - acc;
            img = fmaf(om, S2, img);
            acc = fmaf(om, S1, acc);
        }
        out[slice * PP + (r0 + (split >> 1)) * 128 + (split & 1) * 64 + lane] = img;
    }
}

extern "C" void kernel_launch(void* const* d_in, const int* in_sizes, int n_in,
                              void* d_out, int out_size, void* d_ws, size_t ws_size,
                              hipStream_t stream) {
    const float* means  = (const float*)d_in[0];
    const float* scales = (const float*)d_in[1];
    const float* rots   = (const float*)d_in[2];
    const float* ops    = (const float*)d_in[3];
    const float* fts    = (const float*)d_in[4];
    float* out = (float*)d_out;

    float4* gdata = (float4*)d_ws;   // 4*4096*32B = 512 KB

    prep_kernel<<<NG/256, 256, 0, stream>>>(means, scales, rots, ops, fts, gdata);
    render_kernel<<<NSL*64, 1024, 0, stream>>>(gdata, out);
}

// Round 7
// 128.654 us; speedup vs baseline: 1.0200x; 1.0200x over previous
//
#include <hip/hip_runtime.h>

// Medical2DSliceRenderer on MI355X (gfx950) — round 7
//
//   S1[c] = sum_g exp2(qa dx^2 + qb dx dy + qd dy^2 + lop)   (= g*op)
//   S2[c] = sum_g (g*op)^2 * (ft/op)                          (= g^2*op*ft)
//   img = sum_c [prod_{c'<c}(1-S1_c')] * S2_c
//
// Round 7 structure (K$-sharing + high TLP):
//  - render block = 16 waves that ALL scan the SAME 128-gaussian segment
//    (4KB -> scalar-cache resident; waves differ only by pixel rows).
//    Round 6 gave each wave a disjoint 8KB stream (16 streams >> K$) and
//    every unroll-group s_load drain missed to L2 (~200cy ~= measured
//    45cy/iter stall). Sharing the stream makes those drains K$ hits.
//  - no cross-wave reduction -> ZERO LDS; per-(px,chunk,segment) partials
//    go to a global buffer; combine_kernel sums 8 segments/chunk and runs
//    the 4-step recursion. 512 blocks x 16 waves = 8 waves/SIMD.
//  - inner loop = round-5 form (measured 109 busy-cy/iter, best so far).

#define EPSV 1e-6f
#define NG   4096
#define PP   16384
#define NSL  4
#define SEGS 8           // segments per chunk
#define GSEG 128         // gaussians per segment

typedef float v2f __attribute__((ext_vector_type(2)));

static __device__ __forceinline__ v2f splat(float s) { v2f r; r.x = s; r.y = s; return r; }

__global__ void prep_kernel(const float* __restrict__ means,
                            const float* __restrict__ scales,
                            const float* __restrict__ rots,
                            const float* __restrict__ ops,
                            const float* __restrict__ fts,
                            float4* __restrict__ gdata) {
    __shared__ float red[256];
    int tid = threadIdx.x;

    float m = -1e30f;
    for (int i = tid; i < NG; i += 256) m = fmaxf(m, scales[i*3+2]);
    red[tid] = m;
    __syncthreads();
    for (int s = 128; s > 0; s >>= 1) {
        if (tid < s) red[tid] = fmaxf(red[tid], red[tid+s]);
        __syncthreads();
    }
    float maxd = 3.0f * red[0];

    int g = blockIdx.x * 256 + tid;
    if (g >= NG) return;

    float qw = rots[g*4+0], qx = rots[g*4+1], qy = rots[g*4+2], qz = rots[g*4+3];
    float inorm = rsqrtf(qw*qw + qx*qx + qy*qy + qz*qz);
    qw *= inorm; qx *= inorm; qy *= inorm; qz *= inorm;

    float s0 = scales[g*3+0], s1 = scales[g*3+1], s2 = scales[g*3+2];

    float r00 = 1.f - 2.f*(qy*qy + qz*qz), r01 = 2.f*(qx*qy - qw*qz), r02 = 2.f*(qx*qz + qw*qy);
    float r10 = 2.f*(qx*qy + qw*qz), r11 = 1.f - 2.f*(qx*qx + qz*qz), r12 = 2.f*(qy*qz - qw*qx);
    float r20 = 2.f*(qx*qz - qw*qy), r21 = 2.f*(qy*qz + qw*qx), r22 = 1.f - 2.f*(qx*qx + qy*qy);

    float a00 = r00*s0, a01 = r01*s1, a02 = r02*s2;
    float a10 = r10*s0, a11 = r11*s1, a12 = r12*s2;
    float a20 = r20*s0, a21 = r21*s1, a22 = r22*s2;

    float c00 = a00*a00 + a01*a01 + a02*a02;
    float c01 = a00*a10 + a01*a11 + a02*a12;
    float c02 = a00*a20 + a01*a21 + a02*a22;
    float c11 = a10*a10 + a11*a11 + a12*a12;
    float c12 = a10*a20 + a11*a21 + a12*a22;
    float c22 = a20*a20 + a21*a21 + a22*a22;

    float izz = 1.0f / (c22 + EPSV);
    float kx = c02 * izz, ky = c12 * izz;
    float sa = c00 - c02*c02*izz + EPSV;
    float sb = c01 - c02*c12*izz;
    float sd = c11 - c12*c12*izz + EPSV;
    float det = sa*sd - sb*sb;
    float idet = 1.0f / det;

    const float C0 = -0.72134752044448170f;   // -0.5 * log2(e)
    float qa = C0 * sd * idet;
    float qb = C0 * (-2.0f * sb * idet);
    float qd = C0 * sa * idet;

    float mx = means[g*3+0], my = means[g*3+1], mz = means[g*3+2];
    float op = ops[g], ft = fts[g];

    #pragma unroll
    for (int s = 0; s < NSL; ++s) {
        float z = -0.15f + 0.1f * (float)s;
        float zoff = z - mz;
        float m2x = mx + kx * zoff;
        float m2y = my + ky * zoff;
        bool live = (fabsf(mz - z) < maxd) && (op > 1e-12f);
        float lop  = live ? __log2f(op) : -__builtin_inff();
        float ftop = live ? ft / op     : 0.f;
        float4* o = gdata + ((size_t)(s*NG + g)) * 2;
        o[0] = make_float4(-m2x, -m2y, qa, qb);
        o[1] = make_float4( qd,   lop,  ftop, 0.f);
    }
}

// 512 blocks x 1024 threads. block b: px-group = b>>5 (slice, 32-row band),
// split = b&31 -> (chunk = split>>3, segment = split&7). All 16 waves of the
// block stream the SAME segment; wave w covers rows {r0, r0+1}, 4 px/lane.
__global__ __launch_bounds__(1024, 8)
void render_kernel(const float4* __restrict__ gdata, float2* __restrict__ part) {
    int tid   = threadIdx.x;
    int lane  = tid & 63;
    int w     = __builtin_amdgcn_readfirstlane(tid >> 6);   // 0..15
    int b     = blockIdx.x;
    int pxg   = b >> 5;          // 0..15: (slice, row-band)
    int split = b & 31;          // 0..31: (chunk, segment)
    int slice = pxg >> 2;
    int r0    = (pxg & 3) * 32 + w * 2;
    int chunk = split >> 3;
    int seg   = split & 7;

    const float DL = 2.0f / 127.0f;
    v2f xP;  xP.x = -1.0f + (float)lane * DL;  xP.y = xP.x + 64.0f * DL;
    v2f yP0 = splat(-1.0f + (float)r0 * DL);
    v2f yP1 = splat(-1.0f + (float)(r0 + 1) * DL);

    const float4* p = gdata + ((size_t)slice * NG + chunk * 1024 + seg * GSEG) * 2;

    v2f a10 = {0.f,0.f}, a11 = {0.f,0.f}, a20 = {0.f,0.f}, a21 = {0.f,0.f};
    #pragma unroll 8
    for (int g = 0; g < GSEG; ++g) {
        float4 A = p[2*g+0];           // -m2x, -m2y, qa, qb  (s_load, K$-shared)
        float4 B = p[2*g+1];           // qd, lop, ftop, pad
        v2f dx  = xP  + splat(A.x);
        v2f dy0 = yP0 + splat(A.y);
        v2f dy1 = yP1 + splat(A.y);
        v2f t0  = __builtin_elementwise_fma(splat(A.z), dx, splat(A.w) * dy0);
        v2f t1  = __builtin_elementwise_fma(splat(A.z), dx, splat(A.w) * dy1);
        v2f e0  = __builtin_elementwise_fma(splat(B.x) * dy0, dy0, splat(B.y));
        v2f e1  = __builtin_elementwise_fma(splat(B.x) * dy1, dy1, splat(B.y));
        v2f mm0 = __builtin_elementwise_fma(dx, t0, e0);
        v2f mm1 = __builtin_elementwise_fma(dx, t1, e1);
        v2f gv0, gv1;
        gv0.x = __builtin_amdgcn_exp2f(mm0.x);
        gv0.y = __builtin_amdgcn_exp2f(mm0.y);
        gv1.x = __builtin_amdgcn_exp2f(mm1.x);
        gv1.y = __builtin_amdgcn_exp2f(mm1.y);
        a10 += gv0;
        a11 += gv1;
        a20 = __builtin_elementwise_fma(gv0 * gv0, splat(B.z), a20);
        a21 = __builtin_elementwise_fma(gv1 * gv1, splat(B.z), a21);
    }

    // partials: part[px*32 + chunk*8 + seg] = {S1, S2}
    size_t o = ((size_t)(slice * PP + r0 * 128 + lane)) * 32 + chunk * 8 + seg;
    part[o           ] = make_float2(a10.x, a20.x);   // (r0,   lane)
    part[o +  64 * 32] = make_float2(a10.y, a20.y);   // (r0,   lane+64)
    part[o + 128 * 32] = make_float2(a11.x, a21.x);   // (r0+1, lane)
    part[o + 192 * 32] = make_float2(a11.y, a21.y);   // (r0+1, lane+64)
}

// one thread per pixel: sum 8 segment-partials per chunk, 4-step recursion
__global__ __launch_bounds__(256)
void combine_kernel(const float2* __restrict__ part, float* __restrict__ out) {
    int px = blockIdx.x * 256 + threadIdx.x;
    const float2* q = part + (size_t)px * 32;
    float img = 0.f, acc = 0.f;
    #pragma unroll
    for (int c = 0; c < 4; ++c) {
        float S1 = 0.f, S2 = 0.f;
        #pragma unroll
        for (int s = 0; s < SEGS; ++s) {
            float2 v = q[c*8 + s];
            S1 += v.x;  S2 += v.y;
        }
        float om = 1.0f - acc;
        img = fmaf(om, S2, img);
        acc = fmaf(om, S1, acc);
    }
    out[px] = img;
}

extern "C" void kernel_launch(void* const* d_in, const int* in_sizes, int n_in,
                              void* d_out, int out_size, void* d_ws, size_t ws_size,
                              hipStream_t stream) {
    const float* means  = (const float*)d_in[0];
    const float* scales = (const float*)d_in[1];
    const float* rots   = (const float*)d_in[2];
    const float* ops    = (const float*)d_in[3];
    const float* fts    = (const float*)d_in[4];
    float* out = (float*)d_out;

    float4* gdata = (float4*)d_ws;                          // 512 KB
    float2* part  = (float2*)((char*)d_ws + (size_t)NSL*NG*32);  // 16.8 MB

    prep_kernel<<<NG/256, 256, 0, stream>>>(means, scales, rots, ops, fts, gdata);
    render_kernel<<<512, 1024, 0, stream>>>(gdata, part);
    combine_kernel<<<NSL*PP/256, 256, 0, stream>>>(part, out);
}